// Round 10
// baseline (46.714 us; speedup 1.0000x reference)
//
#include <hip/hip_runtime.h>
#include <math.h>

#define BS 256            // block size
#define NB 2048           // grid for both big kernels (8 blocks/CU)
#define NWAVES (BS / 64)
#define NSLOT 64          // spread join slots (one 128-B line each)
#define PER_SLOT (NB / NSLOT)     // 32 arrivals per slot
#define FXS 4294967296.0  // 2^32 fixed-point scale (deterministic integer join)

// ws layout (bytes):
//   [0,     16384)  double bsum[2048]   (plain stores, no init needed)
//   [16384, 32768)  double bss[2048]
//   [32768, 40960)  float  bmn[2048]
//   [40960, 49152)  float  bmx[2048]
//   [49408, 57600)  int64 loss slot i at 49408 + i*128  (zeroed by k_stats blk 0)
//   [57600, 65792)  u32   cnt  slot i at 57600 + i*128  (zeroed by k_stats blk 0)

// ---------- wave reduction helpers ----------
__device__ inline double wred_sum(double v) {
#pragma unroll
    for (int o = 32; o > 0; o >>= 1) v += __shfl_down(v, o, 64);
    return v;
}
__device__ inline float wred_min(float v) {
#pragma unroll
    for (int o = 32; o > 0; o >>= 1) v = fminf(v, __shfl_down(v, o, 64));
    return v;
}
__device__ inline float wred_max(float v) {
#pragma unroll
    for (int o = 32; o > 0; o >>= 1) v = fmaxf(v, __shfl_down(v, o, 64));
    return v;
}

__device__ inline void acc_stats(float4 v, double& s, double& ss, float& mn, float& mx) {
    mn = fminf(mn, fminf(fminf(v.x, v.y), fminf(v.z, v.w)));
    mx = fmaxf(mx, fmaxf(fmaxf(v.x, v.y), fmaxf(v.z, v.w)));
    s += (double)v.x + (double)v.y + (double)v.z + (double)v.w;
    ss += (double)v.x * v.x + (double)v.y * v.y
        + (double)v.z * v.z + (double)v.w * v.w;
}

// ---------- dispatch 1: per-block {sum, sumsq, min, max} over targets ----------
__global__ void __launch_bounds__(BS) k_stats(
        const float* __restrict__ t, int n,
        double* __restrict__ bsum, double* __restrict__ bss,
        float* __restrict__ bmn, float* __restrict__ bmx,
        char* __restrict__ slots) {
    // block 0 zeroes the join slots (plain stores; dispatch boundary publishes)
    if (blockIdx.x == 0) {
        if (threadIdx.x < NSLOT)
            *(long long*)(slots + (size_t)threadIdx.x * 128) = 0ll;
        else if (threadIdx.x < 2 * NSLOT)
            *(unsigned*)(slots + 8192 + (size_t)(threadIdx.x - NSLOT) * 128) = 0u;
    }

    int n4 = n >> 2;
    int cpb = (n4 + NB - 1) / NB;             // float4s per block (contiguous chunk)
    int start = blockIdx.x * cpb;
    int end = min(start + cpb, n4);
    const float4* t4 = (const float4*)t;

    double s = 0.0, ss = 0.0;
    float mn = 3.4e38f, mx = -3.4e38f;
    int i = start + threadIdx.x;
    for (; i + 3 * BS < end; i += 4 * BS) {   // 4 loads in flight, 4 KB apart
        float4 a = t4[i];
        float4 b = t4[i + BS];
        float4 c = t4[i + 2 * BS];
        float4 d = t4[i + 3 * BS];
        acc_stats(a, s, ss, mn, mx);
        acc_stats(b, s, ss, mn, mx);
        acc_stats(c, s, ss, mn, mx);
        acc_stats(d, s, ss, mn, mx);
    }
    for (; i < end; i += BS) {
        float4 a = t4[i];
        acc_stats(a, s, ss, mn, mx);
    }
    if (blockIdx.x == 0 && threadIdx.x == 0) {  // scalar tail (n % 4)
        for (int j = (n4 << 2); j < n; j++) {
            float v = t[j];
            mn = fminf(mn, v); mx = fmaxf(mx, v);
            s += v; ss += (double)v * v;
        }
    }

    s = wred_sum(s); ss = wred_sum(ss); mn = wred_min(mn); mx = wred_max(mx);

    __shared__ double sh_s[NWAVES], sh_ss[NWAVES];
    __shared__ float sh_mn[NWAVES], sh_mx[NWAVES];
    int wid = threadIdx.x >> 6, lane = threadIdx.x & 63;
    if (lane == 0) { sh_s[wid] = s; sh_ss[wid] = ss; sh_mn[wid] = mn; sh_mx[wid] = mx; }
    __syncthreads();
    if (threadIdx.x == 0) {
        double S = sh_s[0], SS = sh_ss[0];
        float MN = sh_mn[0], MX = sh_mx[0];
        for (int k = 1; k < NWAVES; k++) {
            S += sh_s[k]; SS += sh_ss[k];
            MN = fminf(MN, sh_mn[k]); MX = fmaxf(MX, sh_mx[k]);
        }
        bsum[blockIdx.x] = S; bss[blockIdx.x] = SS;
        bmn[blockIdx.x] = MN; bmx[blockIdx.x] = MX;
    }
}

// ---------- dispatch 2: fold + weighted L1 + spread-slot join ----------
__device__ inline float welem(float g, float x, float gmin, float m1, float m2,
                              float sl, float sm, float shv) {
    float d = fabsf(g - x);
    float wlo = (g - gmin) * sl;
    float wmi = fmaf(g - m1, sm, 0.2f);
    float whi = fmaf(g - m2, shv, 0.7f);
    float w = (g <= m1) ? wlo : ((g <= m2) ? wmi : whi);
    return d * w;
}

__device__ inline float wquad(float4 tv, float4 xv, float gmin, float m1,
                              float m2, float sl, float sm, float shv) {
    return welem(tv.x, xv.x, gmin, m1, m2, sl, sm, shv)
         + welem(tv.y, xv.y, gmin, m1, m2, sl, sm, shv)
         + welem(tv.z, xv.z, gmin, m1, m2, sl, sm, shv)
         + welem(tv.w, xv.w, gmin, m1, m2, sl, sm, shv);
}

__global__ void __launch_bounds__(BS) k_loss(
        const float* __restrict__ x, const float* __restrict__ t, int n,
        const double* __restrict__ sbsum, const double* __restrict__ sbss,
        const float* __restrict__ sbmn, const float* __restrict__ sbmx,
        char* __restrict__ slots, float* __restrict__ out) {
    // --- redundant stats fold: identical order in every block -> identical stats
    __shared__ double sh_s[NWAVES], sh_ss[NWAVES];
    __shared__ float sh_mn[NWAVES], sh_mx[NWAVES];
    __shared__ float s_c[8];
    {
        double s = 0.0, ss = 0.0;
        float mn = 3.4e38f, mx = -3.4e38f;
        for (int i = threadIdx.x; i < NB; i += BS) {
            s += sbsum[i]; ss += sbss[i];
            mn = fminf(mn, sbmn[i]); mx = fmaxf(mx, sbmx[i]);
        }
        s = wred_sum(s); ss = wred_sum(ss); mn = wred_min(mn); mx = wred_max(mx);
        int wid = threadIdx.x >> 6, lane = threadIdx.x & 63;
        if (lane == 0) { sh_s[wid] = s; sh_ss[wid] = ss; sh_mn[wid] = mn; sh_mx[wid] = mx; }
        __syncthreads();
        if (threadIdx.x == 0) {
            double S = sh_s[0], SS = sh_ss[0];
            float MN = sh_mn[0], MX = sh_mx[0];
            for (int k = 1; k < NWAVES; k++) {
                S += sh_s[k]; SS += sh_ss[k];
                MN = fminf(MN, sh_mn[k]); MX = fmaxf(MX, sh_mx[k]);
            }
            double dn = (double)n;
            double mean = S / dn;
            double var = (SS - S * S / dn) / (dn - 1.0);   // ddof=1
            double sd = sqrt(var);
            float m1 = (float)(mean + sd);
            float m2 = (float)(mean + 3.0 * sd);
            s_c[0] = MN;                  // gmin
            s_c[1] = m1;
            s_c[2] = m2;
            s_c[3] = 0.2f / (m1 - MN);    // low slope
            s_c[4] = 0.5f / (m2 - m1);    // mid slope
            s_c[5] = 0.3f / (MX - m2);    // high slope
        }
        __syncthreads();
    }
    float gmin = s_c[0], m1 = s_c[1], m2 = s_c[2];
    float sl = s_c[3], sm = s_c[4], shv = s_c[5];

    int n4 = n >> 2;
    int cpb = (n4 + NB - 1) / NB;
    int start = blockIdx.x * cpb;
    int end = min(start + cpb, n4);
    const float4* x4 = (const float4*)x;
    const float4* t4 = (const float4*)t;

    double acc = 0.0;
    int i = start + threadIdx.x;
    for (; i + 3 * BS < end; i += 4 * BS) {   // 8 loads in flight; cold x first
        float4 xa = x4[i];
        float4 xb = x4[i + BS];
        float4 xc = x4[i + 2 * BS];
        float4 xd = x4[i + 3 * BS];
        float4 ta = t4[i];
        float4 tb = t4[i + BS];
        float4 tc = t4[i + 2 * BS];
        float4 td = t4[i + 3 * BS];
        float e0 = wquad(ta, xa, gmin, m1, m2, sl, sm, shv);
        float e1 = wquad(tb, xb, gmin, m1, m2, sl, sm, shv);
        float e2 = wquad(tc, xc, gmin, m1, m2, sl, sm, shv);
        float e3 = wquad(td, xd, gmin, m1, m2, sl, sm, shv);
        acc += (double)(e0 + e1) + (double)(e2 + e3);
    }
    for (; i < end; i += BS) {
        float4 tv = t4[i], xv = x4[i];
        acc += (double)wquad(tv, xv, gmin, m1, m2, sl, sm, shv);
    }
    if (blockIdx.x == 0 && threadIdx.x == 0) {  // scalar tail (n % 4)
        for (int j = (n4 << 2); j < n; j++)
            acc += (double)welem(t[j], x[j], gmin, m1, m2, sl, sm, shv);
    }

    acc = wred_sum(acc);
    __shared__ double sh_acc[NWAVES];
    __shared__ int s_fin;
    int wid = threadIdx.x >> 6, lane = threadIdx.x & 63;
    if (lane == 0) sh_acc[wid] = acc;
    __syncthreads();
    if (threadIdx.x == 0) {
        double S = sh_acc[0];
        for (int k = 1; k < NWAVES; k++) S += sh_acc[k];
        int slot = blockIdx.x & (NSLOT - 1);
        long long* lslot = (long long*)(slots + (size_t)slot * 128);
        unsigned*  cslot = (unsigned*)(slots + 8192 + (size_t)slot * 128);
        // value travels THROUGH a relaxed agent-scope atomic (no fences)
        __hip_atomic_fetch_add(lslot, (long long)llrint(S * FXS),
                               __ATOMIC_RELAXED, __HIP_MEMORY_SCOPE_AGENT);
        asm volatile("s_waitcnt vmcnt(0)" ::: "memory");   // value RMW committed
        unsigned prev = __hip_atomic_fetch_add(cslot, 1u,
                               __ATOMIC_RELAXED, __HIP_MEMORY_SCOPE_AGENT);
        s_fin = (prev == PER_SLOT - 1) ? 1 : 0;   // this block filled its slot
    }
    __syncthreads();
    if (!s_fin) return;

    // ---- the 64 slot-filling blocks spin until all 2048 arrived, then all
    // compute the identical final value (benign redundant stores). ----
    if (threadIdx.x < 64) {
        unsigned total;
        do {
            unsigned c = __hip_atomic_load(
                (unsigned*)(slots + 8192 + (size_t)threadIdx.x * 128),
                __ATOMIC_RELAXED, __HIP_MEMORY_SCOPE_AGENT);
#pragma unroll
            for (int o = 32; o > 0; o >>= 1) c += __shfl_down(c, o, 64);
            total = __shfl(c, 0, 64);
            if (total != NB) __builtin_amdgcn_s_sleep(32);
        } while (total != NB);
        long long v = __hip_atomic_load(
            (long long*)(slots + (size_t)threadIdx.x * 128),
            __ATOMIC_RELAXED, __HIP_MEMORY_SCOPE_AGENT);
#pragma unroll
        for (int o = 32; o > 0; o >>= 1) v += __shfl_down(v, o, 64);
        if (threadIdx.x == 0)
            out[0] = (float)(((double)v / FXS) / (double)n);
    }
}

extern "C" void kernel_launch(void* const* d_in, const int* in_sizes, int n_in,
                              void* d_out, int out_size, void* d_ws, size_t ws_size,
                              hipStream_t stream) {
    const float* inp = (const float*)d_in[0];
    const float* tgt = (const float*)d_in[1];
    int n = in_sizes[0];

    char* ws = (char*)d_ws;
    double* sum1  = (double*)(ws);
    double* ss1   = (double*)(ws + 16384);
    float*  mn1   = (float*)(ws + 32768);
    float*  mx1   = (float*)(ws + 40960);
    char*   slots = ws + 49408;   // [0,8192): int64 slots, [8192,16384): counters

    k_stats<<<NB, BS, 0, stream>>>(tgt, n, sum1, ss1, mn1, mx1, slots);
    k_loss<<<NB, BS, 0, stream>>>(inp, tgt, n, sum1, ss1, mn1, mx1,
                                  slots, (float*)d_out);
}

// Round 11
// 46.299 us; speedup vs baseline: 1.0090x; 1.0090x over previous
//
#include <hip/hip_runtime.h>
#include <math.h>

#define BS 256
#define NWAVES (BS / 64)

// ---- one-pass histogram path ----
#define NBM 512            // main-kernel grid (2 blocks/CU)
#define NBINS 256          // t-bins over [-16,16), width 1/8
#define NCOL (2 * NBINS)   // u64 columns per block partial (|d| and |d|t)
#define NFOLD (NCOL / 16)  // fold blocks, 16 columns each
#define TBS2 512
#define FXSC 1048576.0f    // 2^20 fixed-point scale
#define WS_NEEDED (16384 + (size_t)NBM * NCOL * 8)

// ---- fallback (round-8/9 proven) ----
#define NB 2048
#define TBS 1024
#define TNW (TBS / 64)

// ---------- wave reduction helpers ----------
__device__ inline double wred_sum(double v) {
#pragma unroll
    for (int o = 32; o > 0; o >>= 1) v += __shfl_down(v, o, 64);
    return v;
}
__device__ inline float wred_min(float v) {
#pragma unroll
    for (int o = 32; o > 0; o >>= 1) v = fminf(v, __shfl_down(v, o, 64));
    return v;
}
__device__ inline float wred_max(float v) {
#pragma unroll
    for (int o = 32; o > 0; o >>= 1) v = fmaxf(v, __shfl_down(v, o, 64));
    return v;
}

// =====================================================================
// PATH A: single streaming pass + histogram join
// =====================================================================

// per-element: stats + region-agnostic weighted-L1 decomposition into bins
__device__ inline void proc1(float g, float xx,
                             double& s, double& ss, float& mn, float& mx,
                             unsigned long long* hist) {
    mn = fminf(mn, g); mx = fmaxf(mx, g);
    s += (double)g; ss += (double)g * g;
    float d = fabsf(g - xx);
    int bin = (int)fmaf(g, 8.0f, 128.0f);          // [-16,16) -> [0,256)
    bin = min(max(bin, 0), NBINS - 1);
    unsigned long long ad = (unsigned long long)(unsigned)(d * FXSC);
    long long gd = (long long)(int)(d * g * FXSC); // signed, |.| < 2^27
    atomicAdd(&hist[2 * bin], ad);
    atomicAdd(&hist[2 * bin + 1], (unsigned long long)gd);
}

__global__ void __launch_bounds__(BS) k_main(
        const float* __restrict__ x, const float* __restrict__ t, int n,
        double* __restrict__ bsum, double* __restrict__ bss,
        float* __restrict__ bmn, float* __restrict__ bmx,
        unsigned long long* __restrict__ hist_g) {
    __shared__ unsigned long long hist[NCOL];      // 4 KB
    for (int c = threadIdx.x; c < NCOL; c += BS) hist[c] = 0ull;
    __syncthreads();

    int n4 = n >> 2;
    int cpb = (n4 + NBM - 1) / NBM;                // contiguous chunk per block
    int start = blockIdx.x * cpb;
    int end = min(start + cpb, n4);
    const float4* x4 = (const float4*)x;
    const float4* t4 = (const float4*)t;

    double s = 0.0, ss = 0.0;
    float mn = 3.4e38f, mx = -3.4e38f;

    int i = start + threadIdx.x;
    for (; i + BS < end; i += 2 * BS) {            // 4 loads in flight
        float4 ta = t4[i];       float4 xa = x4[i];
        float4 tb = t4[i + BS];  float4 xb = x4[i + BS];
        proc1(ta.x, xa.x, s, ss, mn, mx, hist);
        proc1(ta.y, xa.y, s, ss, mn, mx, hist);
        proc1(ta.z, xa.z, s, ss, mn, mx, hist);
        proc1(ta.w, xa.w, s, ss, mn, mx, hist);
        proc1(tb.x, xb.x, s, ss, mn, mx, hist);
        proc1(tb.y, xb.y, s, ss, mn, mx, hist);
        proc1(tb.z, xb.z, s, ss, mn, mx, hist);
        proc1(tb.w, xb.w, s, ss, mn, mx, hist);
    }
    for (; i < end; i += BS) {
        float4 ta = t4[i]; float4 xa = x4[i];
        proc1(ta.x, xa.x, s, ss, mn, mx, hist);
        proc1(ta.y, xa.y, s, ss, mn, mx, hist);
        proc1(ta.z, xa.z, s, ss, mn, mx, hist);
        proc1(ta.w, xa.w, s, ss, mn, mx, hist);
    }
    if (blockIdx.x == 0 && threadIdx.x == 0) {     // scalar tail (n % 4)
        for (int j = (n4 << 2); j < n; j++)
            proc1(t[j], x[j], s, ss, mn, mx, hist);
    }

    __syncthreads();                               // all LDS atomics done
    // flush histogram partial (coalesced row)
    for (int c = threadIdx.x; c < NCOL; c += BS)
        hist_g[(size_t)blockIdx.x * NCOL + c] = hist[c];

    // stats partial
    s = wred_sum(s); ss = wred_sum(ss); mn = wred_min(mn); mx = wred_max(mx);
    __shared__ double sh_s[NWAVES], sh_ss[NWAVES];
    __shared__ float sh_mn[NWAVES], sh_mx[NWAVES];
    int wid = threadIdx.x >> 6, lane = threadIdx.x & 63;
    if (lane == 0) { sh_s[wid] = s; sh_ss[wid] = ss; sh_mn[wid] = mn; sh_mx[wid] = mx; }
    __syncthreads();
    if (threadIdx.x == 0) {
        double S = sh_s[0], SS = sh_ss[0];
        float MN = sh_mn[0], MX = sh_mx[0];
        for (int k = 1; k < NWAVES; k++) {
            S += sh_s[k]; SS += sh_ss[k];
            MN = fminf(MN, sh_mn[k]); MX = fmaxf(MX, sh_mx[k]);
        }
        bsum[blockIdx.x] = S; bss[blockIdx.x] = SS;
        bmn[blockIdx.x] = MN; bmx[blockIdx.x] = MX;
    }
}

// fold: 32 blocks x 16 columns; integer adds -> order-free deterministic
__global__ void __launch_bounds__(BS) k_fold(
        const unsigned long long* __restrict__ hist_g,
        unsigned long long* __restrict__ folded) {
    int bl = threadIdx.x & 15;
    int pl = threadIdx.x >> 4;            // 0..15
    int col = blockIdx.x * 16 + bl;
    unsigned long long v = 0ull;
    for (int p = pl; p < NBM; p += 16)    // coalesced 16-wide reads
        v += hist_g[(size_t)p * NCOL + col];
    __shared__ unsigned long long sh[16][17];
    sh[pl][bl] = v;
    __syncthreads();
    if (pl == 0) {
        unsigned long long acc = 0ull;
        for (int k = 0; k < 16; k++) acc += sh[k][bl];
        folded[col] = acc;
    }
}

// final: stats -> m1,m2 -> per-bin affine weights -> mean
__global__ void __launch_bounds__(TBS2) k_final2(
        const double* __restrict__ bsum, const double* __restrict__ bss,
        const float* __restrict__ bmn, const float* __restrict__ bmx,
        const unsigned long long* __restrict__ folded,
        long long n, float* __restrict__ out) {
    int tid = threadIdx.x;
    double s = bsum[tid], ss = bss[tid];          // NBM == TBS2
    float mn = bmn[tid], mx = bmx[tid];
    s = wred_sum(s); ss = wred_sum(ss); mn = wred_min(mn); mx = wred_max(mx);
    __shared__ double sh_s[TBS2 / 64], sh_ss[TBS2 / 64];
    __shared__ float sh_mn[TBS2 / 64], sh_mx[TBS2 / 64];
    __shared__ double cst[8];
    int wid = tid >> 6, lane = tid & 63;
    if (lane == 0) { sh_s[wid] = s; sh_ss[wid] = ss; sh_mn[wid] = mn; sh_mx[wid] = mx; }
    __syncthreads();
    if (tid == 0) {
        double S = 0.0, SS = 0.0;
        float MN = 3.4e38f, MX = -3.4e38f;
        for (int k = 0; k < TBS2 / 64; k++) {
            S += sh_s[k]; SS += sh_ss[k];
            MN = fminf(MN, sh_mn[k]); MX = fmaxf(MX, sh_mx[k]);
        }
        double dn = (double)n;
        double mean = S / dn;
        double var = (SS - S * S / dn) / (dn - 1.0);   // ddof=1
        double sd = sqrt(var);
        double m1 = mean + sd, m2 = mean + 3.0 * sd;
        double gmin = MN, gmax = MX;
        double sl = 0.2 / (m1 - gmin);
        double sm = 0.5 / (m2 - m1);
        double shp = 0.3 / (gmax - m2);
        cst[0] = m1;  cst[1] = m2;
        cst[2] = -gmin * sl;       cst[3] = sl;    // low  : w = a + b t
        cst[4] = 0.2 - m1 * sm;    cst[5] = sm;    // mid
        cst[6] = 0.7 - m2 * shp;   cst[7] = shp;   // high
    }
    __syncthreads();
    double contrib = 0.0;
    if (tid < NBINS) {
        double A = (double)folded[2 * tid];                 // sum |d| (fx)
        double G = (double)(long long)folded[2 * tid + 1];  // sum |d| t (fx)
        double c = (tid + 0.5) * 0.125 - 16.0;              // bin center
        double al, be;
        if (c <= cst[0]) { al = cst[2]; be = cst[3]; }
        else if (c <= cst[1]) { al = cst[4]; be = cst[5]; }
        else { al = cst[6]; be = cst[7]; }
        contrib = al * A + be * G;
    }
    contrib = wred_sum(contrib);
    __shared__ double sh_c[TBS2 / 64];
    if (lane == 0) sh_c[wid] = contrib;
    __syncthreads();
    if (tid == 0) {
        double T = 0.0;
        for (int k = 0; k < TBS2 / 64; k++) T += sh_c[k];
        out[0] = (float)((T / (double)FXSC) / (double)n);
    }
}

// =====================================================================
// PATH B: fallback (round-8/9 proven 4-dispatch), used if ws too small
// =====================================================================
__device__ inline void acc_stats(float4 v, double& s, double& ss, float& mn, float& mx) {
    mn = fminf(mn, fminf(fminf(v.x, v.y), fminf(v.z, v.w)));
    mx = fmaxf(mx, fmaxf(fmaxf(v.x, v.y), fmaxf(v.z, v.w)));
    s += (double)v.x + (double)v.y + (double)v.z + (double)v.w;
    ss += (double)v.x * v.x + (double)v.y * v.y
        + (double)v.z * v.z + (double)v.w * v.w;
}

__global__ void __launch_bounds__(BS) fb_stats(
        const float* __restrict__ t, int n,
        double* __restrict__ bsum, double* __restrict__ bss,
        float* __restrict__ bmn, float* __restrict__ bmx) {
    int n4 = n >> 2;
    int cpb = (n4 + NB - 1) / NB;
    int start = blockIdx.x * cpb;
    int end = min(start + cpb, n4);
    const float4* t4 = (const float4*)t;
    double s = 0.0, ss = 0.0;
    float mn = 3.4e38f, mx = -3.4e38f;
    int i = start + threadIdx.x;
    for (; i + 3 * BS < end; i += 4 * BS) {
        float4 a = t4[i], b = t4[i + BS], c = t4[i + 2 * BS], d = t4[i + 3 * BS];
        acc_stats(a, s, ss, mn, mx); acc_stats(b, s, ss, mn, mx);
        acc_stats(c, s, ss, mn, mx); acc_stats(d, s, ss, mn, mx);
    }
    for (; i < end; i += BS) { float4 a = t4[i]; acc_stats(a, s, ss, mn, mx); }
    if (blockIdx.x == 0 && threadIdx.x == 0)
        for (int j = (n4 << 2); j < n; j++) {
            float v = t[j];
            mn = fminf(mn, v); mx = fmaxf(mx, v); s += v; ss += (double)v * v;
        }
    s = wred_sum(s); ss = wred_sum(ss); mn = wred_min(mn); mx = wred_max(mx);
    __shared__ double sh_s[NWAVES], sh_ss[NWAVES];
    __shared__ float sh_mn[NWAVES], sh_mx[NWAVES];
    int wid = threadIdx.x >> 6, lane = threadIdx.x & 63;
    if (lane == 0) { sh_s[wid] = s; sh_ss[wid] = ss; sh_mn[wid] = mn; sh_mx[wid] = mx; }
    __syncthreads();
    if (threadIdx.x == 0) {
        double S = sh_s[0], SS = sh_ss[0];
        float MN = sh_mn[0], MX = sh_mx[0];
        for (int k = 1; k < NWAVES; k++) {
            S += sh_s[k]; SS += sh_ss[k];
            MN = fminf(MN, sh_mn[k]); MX = fmaxf(MX, sh_mx[k]);
        }
        bsum[blockIdx.x] = S; bss[blockIdx.x] = SS;
        bmn[blockIdx.x] = MN; bmx[blockIdx.x] = MX;
    }
}

__global__ void __launch_bounds__(TBS) fb_finstats(
        const double* __restrict__ bsum, const double* __restrict__ bss,
        const float* __restrict__ bmn, const float* __restrict__ bmx,
        long long n, float* __restrict__ stats) {
    double s = 0.0, ss = 0.0;
    float mn = 3.4e38f, mx = -3.4e38f;
    for (int i = threadIdx.x; i < NB; i += TBS) {
        s += bsum[i]; ss += bss[i];
        mn = fminf(mn, bmn[i]); mx = fmaxf(mx, bmx[i]);
    }
    s = wred_sum(s); ss = wred_sum(ss); mn = wred_min(mn); mx = wred_max(mx);
    __shared__ double sh_s[TNW], sh_ss[TNW];
    __shared__ float sh_mn[TNW], sh_mx[TNW];
    int wid = threadIdx.x >> 6, lane = threadIdx.x & 63;
    if (lane == 0) { sh_s[wid] = s; sh_ss[wid] = ss; sh_mn[wid] = mn; sh_mx[wid] = mx; }
    __syncthreads();
    if (threadIdx.x == 0) {
        double S = sh_s[0], SS = sh_ss[0];
        float MN = sh_mn[0], MX = sh_mx[0];
        for (int i = 1; i < TNW; i++) {
            S += sh_s[i]; SS += sh_ss[i];
            MN = fminf(MN, sh_mn[i]); MX = fmaxf(MX, sh_mx[i]);
        }
        double dn = (double)n;
        double mean = S / dn;
        double var = (SS - S * S / dn) / (dn - 1.0);
        double sd = sqrt(var);
        float m1 = (float)(mean + sd), m2 = (float)(mean + 3.0 * sd);
        stats[0] = MN; stats[1] = m1; stats[2] = m2; stats[3] = MX;
        stats[4] = 0.2f / (m1 - MN);
        stats[5] = 0.5f / (m2 - m1);
        stats[6] = 0.3f / (MX - m2);
    }
}

__device__ inline float welem(float g, float x, float gmin, float m1, float m2,
                              float sl, float sm, float shv) {
    float d = fabsf(g - x);
    float wlo = (g - gmin) * sl;
    float wmi = fmaf(g - m1, sm, 0.2f);
    float whi = fmaf(g - m2, shv, 0.7f);
    float w = (g <= m1) ? wlo : ((g <= m2) ? wmi : whi);
    return d * w;
}
__device__ inline float wquad(float4 tv, float4 xv, float gmin, float m1,
                              float m2, float sl, float sm, float shv) {
    return welem(tv.x, xv.x, gmin, m1, m2, sl, sm, shv)
         + welem(tv.y, xv.y, gmin, m1, m2, sl, sm, shv)
         + welem(tv.z, xv.z, gmin, m1, m2, sl, sm, shv)
         + welem(tv.w, xv.w, gmin, m1, m2, sl, sm, shv);
}

__global__ void __launch_bounds__(BS) fb_loss(
        const float* __restrict__ x, const float* __restrict__ t, int n,
        const float* __restrict__ stats, double* __restrict__ bsum) {
    float gmin = stats[0], m1 = stats[1], m2 = stats[2];
    float sl = stats[4], sm = stats[5], shv = stats[6];
    int n4 = n >> 2;
    int cpb = (n4 + NB - 1) / NB;
    int start = blockIdx.x * cpb;
    int end = min(start + cpb, n4);
    const float4* x4 = (const float4*)x;
    const float4* t4 = (const float4*)t;
    double acc = 0.0;
    int i = start + threadIdx.x;
    for (; i + 3 * BS < end; i += 4 * BS) {
        float4 xa = x4[i], xb = x4[i + BS], xc = x4[i + 2 * BS], xd = x4[i + 3 * BS];
        float4 ta = t4[i], tb = t4[i + BS], tc = t4[i + 2 * BS], td = t4[i + 3 * BS];
        float e0 = wquad(ta, xa, gmin, m1, m2, sl, sm, shv);
        float e1 = wquad(tb, xb, gmin, m1, m2, sl, sm, shv);
        float e2 = wquad(tc, xc, gmin, m1, m2, sl, sm, shv);
        float e3 = wquad(td, xd, gmin, m1, m2, sl, sm, shv);
        acc += (double)(e0 + e1) + (double)(e2 + e3);
    }
    for (; i < end; i += BS) {
        float4 tv = t4[i], xv = x4[i];
        acc += (double)wquad(tv, xv, gmin, m1, m2, sl, sm, shv);
    }
    if (blockIdx.x == 0 && threadIdx.x == 0)
        for (int j = (n4 << 2); j < n; j++)
            acc += (double)welem(t[j], x[j], gmin, m1, m2, sl, sm, shv);
    acc = wred_sum(acc);
    __shared__ double sh_s[NWAVES];
    int wid = threadIdx.x >> 6, lane = threadIdx.x & 63;
    if (lane == 0) sh_s[wid] = acc;
    __syncthreads();
    if (threadIdx.x == 0) {
        double S = sh_s[0];
        for (int k = 1; k < NWAVES; k++) S += sh_s[k];
        bsum[blockIdx.x] = S;
    }
}

__global__ void __launch_bounds__(TBS) fb_final(
        const double* __restrict__ bsum, long long n, float* __restrict__ out) {
    double s = 0.0;
    for (int i = threadIdx.x; i < NB; i += TBS) s += bsum[i];
    s = wred_sum(s);
    __shared__ double sh_s[TNW];
    int wid = threadIdx.x >> 6, lane = threadIdx.x & 63;
    if (lane == 0) sh_s[wid] = s;
    __syncthreads();
    if (threadIdx.x == 0) {
        double S = sh_s[0];
        for (int i = 1; i < TNW; i++) S += sh_s[i];
        out[0] = (float)(S / (double)n);
    }
}

extern "C" void kernel_launch(void* const* d_in, const int* in_sizes, int n_in,
                              void* d_out, int out_size, void* d_ws, size_t ws_size,
                              hipStream_t stream) {
    const float* inp = (const float*)d_in[0];
    const float* tgt = (const float*)d_in[1];
    int n = in_sizes[0];
    char* ws = (char*)d_ws;

    if (ws_size >= WS_NEEDED) {
        // PATH A layout:
        //   [0,4096)       double bsum[512]
        //   [4096,8192)    double bss[512]
        //   [8192,10240)   float  bmn[512]
        //   [10240,12288)  float  bmx[512]
        //   [12288,16384)  u64    folded[512]
        //   [16384,..)     u64    hist_g[512*512]
        double* bsum = (double*)(ws);
        double* bss  = (double*)(ws + 4096);
        float*  bmn  = (float*)(ws + 8192);
        float*  bmx  = (float*)(ws + 10240);
        unsigned long long* folded = (unsigned long long*)(ws + 12288);
        unsigned long long* hist_g = (unsigned long long*)(ws + 16384);

        k_main<<<NBM, BS, 0, stream>>>(inp, tgt, n, bsum, bss, bmn, bmx, hist_g);
        k_fold<<<NFOLD, BS, 0, stream>>>(hist_g, folded);
        k_final2<<<1, TBS2, 0, stream>>>(bsum, bss, bmn, bmx, folded,
                                         (long long)n, (float*)d_out);
    } else {
        // PATH B layout (old): bsum/bss/bmn/bmx[2048] + stats + bsum2[2048]
        double* sum1  = (double*)(ws);
        double* ss1   = (double*)(ws + 16384);
        float*  mn1   = (float*)(ws + 32768);
        float*  mx1   = (float*)(ws + 40960);
        float*  stats = (float*)(ws + 49152);
        double* sum2  = (double*)(ws + 49280);
        fb_stats<<<NB, BS, 0, stream>>>(tgt, n, sum1, ss1, mn1, mx1);
        fb_finstats<<<1, TBS, 0, stream>>>(sum1, ss1, mn1, mx1, (long long)n, stats);
        fb_loss<<<NB, BS, 0, stream>>>(inp, tgt, n, stats, sum2);
        fb_final<<<1, TBS, 0, stream>>>(sum2, (long long)n, (float*)d_out);
    }
}

// Round 12
// 43.762 us; speedup vs baseline: 1.0675x; 1.0580x over previous
//
#include <hip/hip_runtime.h>
#include <math.h>

#define BS 256          // big-kernel block size
#define NB 2048         // big-kernel grid (8 blocks/CU on 256 CUs)
#define NWAVES (BS / 64)
#define TBS 1024        // fold-kernel block size
#define TNW (TBS / 64)
#define CPB 2048        // float4s per block chunk when n4 == NB*CPB (4096^2 case)

// ---------- wave reduction helpers ----------
__device__ inline double wred_sum(double v) {
#pragma unroll
    for (int o = 32; o > 0; o >>= 1) v += __shfl_down(v, o, 64);
    return v;
}
__device__ inline float wred_min(float v) {
#pragma unroll
    for (int o = 32; o > 0; o >>= 1) v = fminf(v, __shfl_down(v, o, 64));
    return v;
}
__device__ inline float wred_max(float v) {
#pragma unroll
    for (int o = 32; o > 0; o >>= 1) v = fmaxf(v, __shfl_down(v, o, 64));
    return v;
}

__device__ inline void acc_stats(float4 v, double& s, double& ss, float& mn, float& mx) {
    mn = fminf(mn, fminf(fminf(v.x, v.y), fminf(v.z, v.w)));
    mx = fmaxf(mx, fmaxf(fmaxf(v.x, v.y), fmaxf(v.z, v.w)));
    s += (double)v.x + (double)v.y + (double)v.z + (double)v.w;
    ss += (double)v.x * v.x + (double)v.y * v.y
        + (double)v.z * v.z + (double)v.w * v.w;
}

// direct global -> LDS copy, 16 B per lane; lds base must be wave-uniform
__device__ inline void gload16(const float4* g, float4* s) {
    __builtin_amdgcn_global_load_lds(
        (const __attribute__((address_space(1))) void*)g,
        (__attribute__((address_space(3))) void*)s, 16, 0, 0);
}

// ---------- pass 1: per-block {sum, sumsq, min, max} over targets ----------
__global__ void __launch_bounds__(BS) k_stats(
        const float* __restrict__ t, int n,
        double* __restrict__ bsum, double* __restrict__ bss,
        float* __restrict__ bmn, float* __restrict__ bmx) {
    int n4 = n >> 2;
    int cpb = (n4 + NB - 1) / NB;             // float4s per block
    int start = blockIdx.x * cpb;
    int end = min(start + cpb, n4);
    const float4* t4 = (const float4*)t;

    double s = 0.0, ss = 0.0;
    float mn = 3.4e38f, mx = -3.4e38f;
    int i = start + threadIdx.x;
    for (; i + 3 * BS < end; i += 4 * BS) {   // 4 loads in flight, 4 KB apart
        float4 a = t4[i];
        float4 b = t4[i + BS];
        float4 c = t4[i + 2 * BS];
        float4 d = t4[i + 3 * BS];
        acc_stats(a, s, ss, mn, mx);
        acc_stats(b, s, ss, mn, mx);
        acc_stats(c, s, ss, mn, mx);
        acc_stats(d, s, ss, mn, mx);
    }
    for (; i < end; i += BS) {
        float4 a = t4[i];
        acc_stats(a, s, ss, mn, mx);
    }
    if (blockIdx.x == 0 && threadIdx.x == 0) {  // scalar tail (n % 4)
        for (int j = (n4 << 2); j < n; j++) {
            float v = t[j];
            mn = fminf(mn, v); mx = fmaxf(mx, v);
            s += v; ss += (double)v * v;
        }
    }

    s = wred_sum(s); ss = wred_sum(ss); mn = wred_min(mn); mx = wred_max(mx);

    __shared__ double sh_s[NWAVES], sh_ss[NWAVES];
    __shared__ float sh_mn[NWAVES], sh_mx[NWAVES];
    int wid = threadIdx.x >> 6, lane = threadIdx.x & 63;
    if (lane == 0) { sh_s[wid] = s; sh_ss[wid] = ss; sh_mn[wid] = mn; sh_mx[wid] = mx; }
    __syncthreads();
    if (threadIdx.x == 0) {
        double S = sh_s[0], SS = sh_ss[0];
        float MN = sh_mn[0], MX = sh_mx[0];
        for (int k = 1; k < NWAVES; k++) {
            S += sh_s[k]; SS += sh_ss[k];
            MN = fminf(MN, sh_mn[k]); MX = fmaxf(MX, sh_mx[k]);
        }
        bsum[blockIdx.x] = S; bss[blockIdx.x] = SS;
        bmn[blockIdx.x] = MN; bmx[blockIdx.x] = MX;
    }
}

// ---------- pass 2: fold block partials -> piecewise-weight constants ----------
__global__ void __launch_bounds__(TBS) k_finalize_stats(
        const double* __restrict__ bsum, const double* __restrict__ bss,
        const float* __restrict__ bmn, const float* __restrict__ bmx,
        long long n, float* __restrict__ stats) {
    double s = 0.0, ss = 0.0;
    float mn = 3.4e38f, mx = -3.4e38f;
    for (int i = threadIdx.x; i < NB; i += TBS) {
        s += bsum[i]; ss += bss[i];
        mn = fminf(mn, bmn[i]); mx = fmaxf(mx, bmx[i]);
    }
    s = wred_sum(s); ss = wred_sum(ss); mn = wred_min(mn); mx = wred_max(mx);

    __shared__ double sh_s[TNW], sh_ss[TNW];
    __shared__ float sh_mn[TNW], sh_mx[TNW];
    int wid = threadIdx.x >> 6, lane = threadIdx.x & 63;
    if (lane == 0) { sh_s[wid] = s; sh_ss[wid] = ss; sh_mn[wid] = mn; sh_mx[wid] = mx; }
    __syncthreads();
    if (threadIdx.x == 0) {
        double S = sh_s[0], SS = sh_ss[0];
        float MN = sh_mn[0], MX = sh_mx[0];
        for (int i = 1; i < TNW; i++) {
            S += sh_s[i]; SS += sh_ss[i];
            MN = fminf(MN, sh_mn[i]); MX = fmaxf(MX, sh_mx[i]);
        }
        double dn = (double)n;
        double mean = S / dn;
        double var = (SS - S * S / dn) / (dn - 1.0);   // ddof=1
        double sd = sqrt(var);
        float gmin = MN, gmax = MX;
        float m1 = (float)(mean + sd);
        float m2 = (float)(mean + 3.0 * sd);
        stats[0] = gmin;
        stats[1] = m1;
        stats[2] = m2;
        stats[3] = gmax;
        stats[4] = 0.2f / (m1 - gmin);   // low slope
        stats[5] = 0.5f / (m2 - m1);     // mid slope
        stats[6] = 0.3f / (gmax - m2);   // high slope
    }
}

// ---------- pass 3: weighted L1, LDS-staged single-stream bursts ----------
__device__ inline float welem(float g, float x, float gmin, float m1, float m2,
                              float sl, float sm, float shv) {
    float d = fabsf(g - x);
    float wlo = (g - gmin) * sl;
    float wmi = fmaf(g - m1, sm, 0.2f);
    float whi = fmaf(g - m2, shv, 0.7f);
    float w = (g <= m1) ? wlo : ((g <= m2) ? wmi : whi);
    return d * w;
}

__device__ inline float wquad(float4 tv, float4 xv, float gmin, float m1,
                              float m2, float sl, float sm, float shv) {
    return welem(tv.x, xv.x, gmin, m1, m2, sl, sm, shv)
         + welem(tv.y, xv.y, gmin, m1, m2, sl, sm, shv)
         + welem(tv.z, xv.z, gmin, m1, m2, sl, sm, shv)
         + welem(tv.w, xv.w, gmin, m1, m2, sl, sm, shv);
}

__global__ void __launch_bounds__(BS) k_loss(
        const float* __restrict__ x, const float* __restrict__ t, int n,
        const float* __restrict__ stats, double* __restrict__ bsum) {
    float gmin = stats[0], m1 = stats[1], m2 = stats[2];
    float sl = stats[4], sm = stats[5], shv = stats[6];
    int n4 = n >> 2;
    int cpb = (n4 + NB - 1) / NB;
    int start = blockIdx.x * cpb;
    int end = min(start + cpb, n4);
    int len = end - start;
    const float4* x4 = (const float4*)x;
    const float4* t4 = (const float4*)t;

    __shared__ float4 st[CPB];        // 32 KB t-chunk stage
    double acc = 0.0;

    if (cpb == CPB && len == CPB) {
        // --- phase A: single-stream burst t-chunk -> LDS (no VGPR round-trip)
        int w = threadIdx.x >> 6, l = threadIdx.x & 63;
        const float4* gt = t4 + start;
#pragma unroll
        for (int j = 0; j < CPB / BS; ++j) {
            int off = j * BS + w * 64;            // wave-uniform float4 offset
            gload16(gt + off + l, st + off);      // HW adds lane*16 to LDS dest
        }
        asm volatile("s_waitcnt vmcnt(0)" ::: "memory");
        __syncthreads();

        // --- phase B: single-stream burst x-chunk, combine vs LDS ---
#pragma unroll
        for (int j = 0; j < CPB / BS; j += 4) {
            int b = j * BS + threadIdx.x;
            float4 xa = x4[start + b];
            float4 xb = x4[start + b + BS];
            float4 xc = x4[start + b + 2 * BS];
            float4 xd = x4[start + b + 3 * BS];
            float4 ta = st[b];
            float4 tb = st[b + BS];
            float4 tc = st[b + 2 * BS];
            float4 td = st[b + 3 * BS];
            float e0 = wquad(ta, xa, gmin, m1, m2, sl, sm, shv);
            float e1 = wquad(tb, xb, gmin, m1, m2, sl, sm, shv);
            float e2 = wquad(tc, xc, gmin, m1, m2, sl, sm, shv);
            float e3 = wquad(td, xd, gmin, m1, m2, sl, sm, shv);
            acc += (double)(e0 + e1) + (double)(e2 + e3);
        }
    } else {
        // fallback: ragged chunk (generic shapes)
        for (int i = start + threadIdx.x; i < end; i += BS) {
            float4 tv = t4[i], xv = x4[i];
            acc += (double)wquad(tv, xv, gmin, m1, m2, sl, sm, shv);
        }
    }
    if (blockIdx.x == 0 && threadIdx.x == 0) {  // scalar tail (n % 4)
        for (int j = (n4 << 2); j < n; j++)
            acc += (double)welem(t[j], x[j], gmin, m1, m2, sl, sm, shv);
    }

    acc = wred_sum(acc);
    __shared__ double sh_s[NWAVES];
    int wid = threadIdx.x >> 6, lane = threadIdx.x & 63;
    if (lane == 0) sh_s[wid] = acc;
    __syncthreads();
    if (threadIdx.x == 0) {
        double S = sh_s[0];
        for (int k = 1; k < NWAVES; k++) S += sh_s[k];
        bsum[blockIdx.x] = S;
    }
}

// ---------- pass 4: final mean ----------
__global__ void __launch_bounds__(TBS) k_final(
        const double* __restrict__ bsum, long long n, float* __restrict__ out) {
    double s = 0.0;
    for (int i = threadIdx.x; i < NB; i += TBS) s += bsum[i];
    s = wred_sum(s);
    __shared__ double sh_s[TNW];
    int wid = threadIdx.x >> 6, lane = threadIdx.x & 63;
    if (lane == 0) sh_s[wid] = s;
    __syncthreads();
    if (threadIdx.x == 0) {
        double S = sh_s[0];
        for (int i = 1; i < TNW; i++) S += sh_s[i];
        out[0] = (float)(S / (double)n);
    }
}

extern "C" void kernel_launch(void* const* d_in, const int* in_sizes, int n_in,
                              void* d_out, int out_size, void* d_ws, size_t ws_size,
                              hipStream_t stream) {
    const float* inp = (const float*)d_in[0];
    const float* tgt = (const float*)d_in[1];
    int n = in_sizes[0];

    // workspace layout (bytes); plain stores -> no init needed:
    //   [0,      16384) double sum1[NB]
    //   [16384,  32768) double ss1[NB]
    //   [32768,  40960) float  mn1[NB]
    //   [40960,  49152) float  mx1[NB]
    //   [49152,  49216) float  stats[16]
    //   [49280,  65664) double sum2[NB]
    char* ws = (char*)d_ws;
    double* sum1  = (double*)(ws);
    double* ss1   = (double*)(ws + 16384);
    float*  mn1   = (float*)(ws + 32768);
    float*  mx1   = (float*)(ws + 40960);
    float*  stats = (float*)(ws + 49152);
    double* sum2  = (double*)(ws + 49280);

    k_stats<<<NB, BS, 0, stream>>>(tgt, n, sum1, ss1, mn1, mx1);
    k_finalize_stats<<<1, TBS, 0, stream>>>(sum1, ss1, mn1, mx1, (long long)n, stats);
    k_loss<<<NB, BS, 0, stream>>>(inp, tgt, n, stats, sum2);
    k_final<<<1, TBS, 0, stream>>>(sum2, (long long)n, (float*)d_out);
}